// Round 1
// baseline (409.129 us; speedup 1.0000x reference)
//
#include <hip/hip_runtime.h>

#define HIDDEN 2048
#define S_LEN  2048
#define NH     32
#define NKV    8
#define HD     128
#define QKVN   6144   // 4096 q + 1024 k + 1024 v
#define OD     4096   // NH*HD

typedef float  f32x4  __attribute__((ext_vector_type(4)));
typedef __bf16 bf16x8 __attribute__((ext_vector_type(8)));
typedef __bf16 bf16x4 __attribute__((ext_vector_type(4)));

static __device__ __forceinline__ f32x4 mfma16(bf16x8 a, bf16x8 b, f32x4 c) {
  return __builtin_amdgcn_mfma_f32_16x16x32_bf16(a, b, c, 0, 0, 0);
}
static __device__ __forceinline__ void gload_lds16(const void* g, void* l) {
  __builtin_amdgcn_global_load_lds(
      (__attribute__((address_space(1))) void*)(g),
      (__attribute__((address_space(3))) void*)(l), 16, 0, 0);
}

// ---------- fp32 -> bf16 elementwise ----------
__global__ __launch_bounds__(256) void k_cvt(const float* __restrict__ in,
                                             __bf16* __restrict__ out, int n) {
  int i = (blockIdx.x * 256 + threadIdx.x) * 4;
  if (i >= n) return;
  float4 v = *reinterpret_cast<const float4*>(in + i);
  bf16x4 o = {(__bf16)v.x, (__bf16)v.y, (__bf16)v.z, (__bf16)v.w};
  *reinterpret_cast<bf16x4*>(out + i) = o;
}

// ---------- transpose + convert: src (K x N) f32 -> dst (N x K) bf16 ----------
__global__ __launch_bounds__(256) void k_transpose_cvt(const float* __restrict__ src,
                                                       __bf16* __restrict__ dst,
                                                       int K, int N) {
  __shared__ float tile[32][33];
  int tx = threadIdx.x & 31, ty = threadIdx.x >> 5;
  int n0 = blockIdx.x * 32, k0 = blockIdx.y * 32;
#pragma unroll
  for (int r = 0; r < 4; r++) {
    int k = ty + r * 8;
    tile[k][tx] = src[(size_t)(k0 + k) * N + n0 + tx];
  }
  __syncthreads();
#pragma unroll
  for (int r = 0; r < 4; r++) {
    int n = ty + r * 8;
    dst[(size_t)(n0 + n) * K + k0 + tx] = (__bf16)tile[tx][n];
  }
}

__global__ void k_bias_concat(const float* __restrict__ bq, const float* __restrict__ bk,
                              const float* __restrict__ bv, float* __restrict__ out) {
  int i = blockIdx.x * 256 + threadIdx.x;
  if (i >= QKVN) return;
  out[i] = (i < 4096) ? bq[i] : (i < 5120 ? bk[i - 4096] : bv[i - 5120]);
}

// ---------- V transpose: qkv (S x QKVN) v-cols -> vt (NKV x HD x S) ----------
__global__ __launch_bounds__(256) void k_vtrans(const __bf16* __restrict__ qkv,
                                                __bf16* __restrict__ vt) {
  __shared__ __bf16 tile[32][33];
  int tx = threadIdx.x & 31, ty = threadIdx.x >> 5;
  int s0 = blockIdx.x * 32, d0 = blockIdx.y * 32, kv = blockIdx.z;
#pragma unroll
  for (int r = 0; r < 4; r++) {
    int s = ty + r * 8;
    tile[s][tx] = qkv[(size_t)(s0 + s) * QKVN + 5120 + kv * HD + d0 + tx];
  }
  __syncthreads();
#pragma unroll
  for (int r = 0; r < 4; r++) {
    int d = ty + r * 8;
    vt[(size_t)(kv * HD + d0 + d) * S_LEN + s0 + tx] = tile[tx][d];
  }
}

// ---------- GEMM: C (MxN) = A (MxK) @ BT(NxK)^T + bias ----------
// 128x128 tile, BK=64, 4 waves (2x2), global_load_lds w/ pre-swizzled source,
// XOR-swizzled ds_read_b128 (conflict-free), 16x16x32 bf16 MFMA, 4x4 acc/wave.
template <typename OutT>
__global__ __launch_bounds__(256) void k_gemm_bt(const __bf16* __restrict__ A,
                                                 const __bf16* __restrict__ BT,
                                                 const float* __restrict__ bias,
                                                 OutT* __restrict__ C, int M, int N, int K) {
  __shared__ __bf16 Al[128 * 64];
  __shared__ __bf16 Bl[128 * 64];
  const int tid = threadIdx.x;
  const int lane = tid & 63;
  const int w = tid >> 6;
  const int m0 = blockIdx.y * 128;
  const int n0 = blockIdx.x * 128;
  const int wm = (w >> 1) * 64;
  const int wn = (w & 1) * 64;
  const int l15 = lane & 15, lhi = lane >> 4;

  f32x4 acc[4][4];
#pragma unroll
  for (int i = 0; i < 4; i++)
#pragma unroll
    for (int j = 0; j < 4; j++)
#pragma unroll
      for (int e = 0; e < 4; e++) acc[i][j][e] = 0.f;

  for (int kt = 0; kt < K; kt += 64) {
#pragma unroll
    for (int it = 0; it < 4; it++) {
      int idx = it * 256 + tid;
      int row = idx >> 3, slot = idx & 7;
      int scol = ((slot * 16) ^ ((row & 7) << 4)) >> 1;  // element offset in row
      gload_lds16(A + (size_t)(m0 + row) * K + kt + scol, &Al[idx * 8]);
      gload_lds16(BT + (size_t)(n0 + row) * K + kt + scol, &Bl[idx * 8]);
    }
    __syncthreads();
#pragma unroll
    for (int kk = 0; kk < 2; kk++) {
      bf16x8 af[4], bfr[4];
#pragma unroll
      for (int i = 0; i < 4; i++) {
        int ra = wm + i * 16 + l15;
        int ba = (kk * 64 + lhi * 16) ^ ((ra & 7) << 4);
        af[i] = *(const bf16x8*)((const char*)Al + ra * 128 + ba);
        int rb = wn + i * 16 + l15;
        int bb = (kk * 64 + lhi * 16) ^ ((rb & 7) << 4);
        bfr[i] = *(const bf16x8*)((const char*)Bl + rb * 128 + bb);
      }
#pragma unroll
      for (int i = 0; i < 4; i++)
#pragma unroll
        for (int j = 0; j < 4; j++) acc[i][j] = mfma16(af[i], bfr[j], acc[i][j]);
    }
    __syncthreads();
  }
#pragma unroll
  for (int j = 0; j < 4; j++) {
    int col = n0 + wn + j * 16 + l15;
    float bv = bias[col];
#pragma unroll
    for (int i = 0; i < 4; i++) {
      int r0 = m0 + wm + i * 16 + lhi * 4;
#pragma unroll
      for (int rr = 0; rr < 4; rr++) {
        C[(size_t)(r0 + rr) * N + col] = (OutT)(acc[i][j][rr] + bv);
      }
    }
  }
}

// ---------- causal GQA flash attention ----------
// grid (16 q-tiles, 32 heads), 256 threads; wave w owns 32 q-rows.
// K-tile (64x128) and VT-tile (128x64) staged via global_load_lds (swizzled src);
// P goes through per-wave swizzled LDS.
__global__ __launch_bounds__(256) void k_attn(const __bf16* __restrict__ qkv,
                                              const __bf16* __restrict__ vt,
                                              __bf16* __restrict__ o) {
  __shared__ __bf16 Kl[64 * 128];
  __shared__ __bf16 Vl[128 * 64];
  __shared__ __bf16 Pl[4][32 * 64];
  const int tid = threadIdx.x, lane = tid & 63, w = tid >> 6;
  const int l15 = lane & 15, lhi = lane >> 4;
  const int qt = blockIdx.x, head = blockIdx.y, kv = head >> 2;
  const int q_block = qt * 128;
  const int qw = q_block + w * 32;

  // Q fragments from global (one-time, L2-resident)
  bf16x8 qf[2][4];
#pragma unroll
  for (int qs = 0; qs < 2; qs++)
#pragma unroll
    for (int dk = 0; dk < 4; dk++) {
      int qr = qw + qs * 16 + l15;
      int d = dk * 32 + lhi * 8;
      qf[qs][dk] = *(const bf16x8*)(qkv + (size_t)qr * QKVN + head * HD + d);
    }

  f32x4 acc_o[2][8];
#pragma unroll
  for (int qs = 0; qs < 2; qs++)
#pragma unroll
    for (int ds = 0; ds < 8; ds++)
#pragma unroll
      for (int e = 0; e < 4; e++) acc_o[qs][ds][e] = 0.f;
  float mrow[2][4], lrow[2][4];
#pragma unroll
  for (int qs = 0; qs < 2; qs++)
#pragma unroll
    for (int r = 0; r < 4; r++) { mrow[qs][r] = -INFINITY; lrow[qs][r] = 0.f; }

  const float scl = 0.08838834764831845f;  // 1/sqrt(128)
  const int nkt = 2 * qt + 2;
  for (int kt = 0; kt < nkt; kt++) {
    const int k0 = kt * 64;
    // stage K tile (64 keys x 128 d), swizzled source
#pragma unroll
    for (int it = 0; it < 4; it++) {
      int idx = it * 256 + tid;
      int key = idx >> 4, slot = idx & 15;
      int sb = (slot * 16) ^ ((key & 7) << 4);
      gload_lds16(qkv + (size_t)(k0 + key) * QKVN + 4096 + kv * HD + (sb >> 1), &Kl[idx * 8]);
    }
    // stage VT tile (128 d x 64 keys), swizzled source
#pragma unroll
    for (int it = 0; it < 4; it++) {
      int idx = it * 256 + tid;
      int d = idx >> 3, slot = idx & 7;
      int sb = (slot * 16) ^ ((d & 7) << 4);
      gload_lds16(vt + (size_t)(kv * HD + d) * S_LEN + k0 + (sb >> 1), &Vl[idx * 8]);
    }
    __syncthreads();

    if (k0 <= qw + 31) {  // wave has unmasked work in this key tile
      // ---- QK^T ----
      f32x4 sacc[2][4];
#pragma unroll
      for (int qs = 0; qs < 2; qs++)
#pragma unroll
        for (int ks = 0; ks < 4; ks++)
#pragma unroll
          for (int e = 0; e < 4; e++) sacc[qs][ks][e] = 0.f;
#pragma unroll
      for (int dk = 0; dk < 4; dk++) {
        bf16x8 kf[4];
#pragma unroll
        for (int ks = 0; ks < 4; ks++) {
          int kr = ks * 16 + l15;
          int db = (dk * 64 + lhi * 16) ^ ((kr & 7) << 4);
          kf[ks] = *(const bf16x8*)((const char*)Kl + kr * 256 + db);
        }
#pragma unroll
        for (int qs = 0; qs < 2; qs++)
#pragma unroll
          for (int ks = 0; ks < 4; ks++)
            sacc[qs][ks] = mfma16(qf[qs][dk], kf[ks], sacc[qs][ks]);
      }
      // ---- online softmax ----
#pragma unroll
      for (int qs = 0; qs < 2; qs++) {
        float sv[4][4];
        float pm[4];
#pragma unroll
        for (int r = 0; r < 4; r++) {
          int qg = qw + qs * 16 + lhi * 4 + r;
          float mx = -INFINITY;
#pragma unroll
          for (int ks = 0; ks < 4; ks++) {
            int kg = k0 + ks * 16 + l15;
            float s = (kg <= qg) ? sacc[qs][ks][r] * scl : -INFINITY;
            sv[ks][r] = s;
            mx = fmaxf(mx, s);
          }
          pm[r] = mx;
        }
#pragma unroll
        for (int off = 1; off < 16; off <<= 1)
#pragma unroll
          for (int r = 0; r < 4; r++) pm[r] = fmaxf(pm[r], __shfl_xor(pm[r], off));
        float corr[4];
#pragma unroll
        for (int r = 0; r < 4; r++) {
          float mn = fmaxf(mrow[qs][r], pm[r]);
          corr[r] = __expf(mrow[qs][r] - mn);
          mrow[qs][r] = mn;
        }
        float ps[4] = {0.f, 0.f, 0.f, 0.f};
#pragma unroll
        for (int ks = 0; ks < 4; ks++) {
          int keyl = ks * 16 + l15;
#pragma unroll
          for (int r = 0; r < 4; r++) {
            int ql = qs * 16 + lhi * 4 + r;
            float p = __expf(sv[ks][r] - mrow[qs][r]);
            ps[r] += p;
            *(__bf16*)((char*)&Pl[w][0] + ql * 128 + ((keyl * 2) ^ ((ql & 7) << 4))) = (__bf16)p;
          }
        }
#pragma unroll
        for (int r = 0; r < 4; r++) {
          lrow[qs][r] = lrow[qs][r] * corr[r] + ps[r];
#pragma unroll
          for (int ds = 0; ds < 8; ds++) acc_o[qs][ds][r] *= corr[r];
        }
      }
      // ---- PV ---- (P write->read is same-wave; compiler orders LDS ops)
#pragma unroll
      for (int ks2 = 0; ks2 < 2; ks2++) {
        bf16x8 pf[2];
#pragma unroll
        for (int qs = 0; qs < 2; qs++) {
          int ql = qs * 16 + l15;
          int kb = (ks2 * 64 + lhi * 16) ^ ((ql & 7) << 4);
          pf[qs] = *(const bf16x8*)((const char*)&Pl[w][0] + ql * 128 + kb);
        }
#pragma unroll
        for (int ds = 0; ds < 8; ds++) {
          int dr = ds * 16 + l15;
          int kb = (ks2 * 64 + lhi * 16) ^ ((dr & 7) << 4);
          bf16x8 vf = *(const bf16x8*)((const char*)Vl + dr * 128 + kb);
#pragma unroll
          for (int qs = 0; qs < 2; qs++) acc_o[qs][ds] = mfma16(pf[qs], vf, acc_o[qs][ds]);
        }
      }
    }
    __syncthreads();
  }
  // ---- finalize: full row-sum then normalize + write O ----
#pragma unroll
  for (int qs = 0; qs < 2; qs++) {
#pragma unroll
    for (int off = 1; off < 16; off <<= 1)
#pragma unroll
      for (int r = 0; r < 4; r++) lrow[qs][r] += __shfl_xor(lrow[qs][r], off);
#pragma unroll
    for (int r = 0; r < 4; r++) {
      float inv = 1.f / lrow[qs][r];
      int qg = qw + qs * 16 + lhi * 4 + r;
#pragma unroll
      for (int ds = 0; ds < 8; ds++) {
        o[(size_t)qg * OD + head * HD + ds * 16 + l15] = (__bf16)(acc_o[qs][ds][r] * inv);
      }
    }
  }
}

extern "C" void kernel_launch(void* const* d_in, const int* in_sizes, int n_in,
                              void* d_out, int out_size, void* d_ws, size_t ws_size,
                              hipStream_t stream) {
  const float* x  = (const float*)d_in[0];
  // d_in[1] = mask (tril causal; hard-coded in kernel)
  const float* wq = (const float*)d_in[2];
  const float* bq = (const float*)d_in[3];
  const float* wk = (const float*)d_in[4];
  const float* bk = (const float*)d_in[5];
  const float* wv = (const float*)d_in[6];
  const float* bv = (const float*)d_in[7];
  const float* wo = (const float*)d_in[8];
  const float* bo = (const float*)d_in[9];
  float* out = (float*)d_out;

  const size_t MB = 1024 * 1024;
  char* ws = (char*)d_ws;
  __bf16* xb    = (__bf16*)(ws);             //  8 MiB: 2048x2048
  __bf16* wqkvT = (__bf16*)(ws + 8 * MB);    // 24 MiB: 6144x2048 (wq^T|wk^T|wv^T)
  __bf16* woT   = (__bf16*)(ws + 32 * MB);   // 16 MiB: 2048x4096
  __bf16* qkvb  = (__bf16*)(ws + 48 * MB);   // 24 MiB: 2048x6144
  __bf16* vtb   = (__bf16*)(ws + 72 * MB);   //  4 MiB: 8x128x2048
  __bf16* ob    = (__bf16*)(ws + 76 * MB);   // 16 MiB: 2048x4096
  float*  bqkv  = (float*)(ws + 92 * MB);    // 24 KiB

  k_cvt<<<4096, 256, 0, stream>>>(x, xb, HIDDEN * S_LEN);
  k_transpose_cvt<<<dim3(128, 64), 256, 0, stream>>>(wq, wqkvT, HIDDEN, 4096);
  k_transpose_cvt<<<dim3(32, 64), 256, 0, stream>>>(wk, wqkvT + (size_t)4096 * HIDDEN, HIDDEN, 1024);
  k_transpose_cvt<<<dim3(32, 64), 256, 0, stream>>>(wv, wqkvT + (size_t)5120 * HIDDEN, HIDDEN, 1024);
  k_transpose_cvt<<<dim3(64, 128), 256, 0, stream>>>(wo, woT, 4096, HIDDEN);
  k_bias_concat<<<24, 256, 0, stream>>>(bq, bk, bv, bqkv);

  k_gemm_bt<__bf16><<<dim3(QKVN / 128, S_LEN / 128), 256, 0, stream>>>(
      xb, wqkvT, bqkv, qkvb, S_LEN, QKVN, HIDDEN);
  k_vtrans<<<dim3(S_LEN / 32, HD / 32, NKV), 256, 0, stream>>>(qkvb, vtb);
  k_attn<<<dim3(S_LEN / 128, NH), 256, 0, stream>>>(qkvb, vtb, ob);
  k_gemm_bt<float><<<dim3(HIDDEN / 128, S_LEN / 128), 256, 0, stream>>>(
      ob, woT, bo, out, S_LEN, HIDDEN, OD);
}

// Round 2
// 378.067 us; speedup vs baseline: 1.0822x; 1.0822x over previous
//
#include <hip/hip_runtime.h>

#define HIDDEN 2048
#define S_LEN  2048
#define NH     32
#define NKV    8
#define HD     128
#define QKVN   6144   // 4096 q + 1024 k + 1024 v
#define OD     4096   // NH*HD

typedef float  f32x4  __attribute__((ext_vector_type(4)));
typedef __bf16 bf16x8 __attribute__((ext_vector_type(8)));
typedef __bf16 bf16x4 __attribute__((ext_vector_type(4)));

static __device__ __forceinline__ f32x4 mfma16(bf16x8 a, bf16x8 b, f32x4 c) {
  return __builtin_amdgcn_mfma_f32_16x16x32_bf16(a, b, c, 0, 0, 0);
}
static __device__ __forceinline__ void gload_lds16(const void* g, void* l) {
  __builtin_amdgcn_global_load_lds(
      (__attribute__((address_space(1))) void*)(g),
      (__attribute__((address_space(3))) void*)(l), 16, 0, 0);
}

// ---------- fp32 -> bf16 elementwise ----------
__global__ __launch_bounds__(256) void k_cvt(const float* __restrict__ in,
                                             __bf16* __restrict__ out, int n) {
  int i = (blockIdx.x * 256 + threadIdx.x) * 4;
  if (i >= n) return;
  float4 v = *reinterpret_cast<const float4*>(in + i);
  bf16x4 o = {(__bf16)v.x, (__bf16)v.y, (__bf16)v.z, (__bf16)v.w};
  *reinterpret_cast<bf16x4*>(out + i) = o;
}

// ---------- transpose + convert: src (K x N) f32 -> dst (N x K) bf16 ----------
__global__ __launch_bounds__(256) void k_transpose_cvt(const float* __restrict__ src,
                                                       __bf16* __restrict__ dst,
                                                       int K, int N) {
  __shared__ float tile[32][33];
  int tx = threadIdx.x & 31, ty = threadIdx.x >> 5;
  int n0 = blockIdx.x * 32, k0 = blockIdx.y * 32;
#pragma unroll
  for (int r = 0; r < 4; r++) {
    int k = ty + r * 8;
    tile[k][tx] = src[(size_t)(k0 + k) * N + n0 + tx];
  }
  __syncthreads();
#pragma unroll
  for (int r = 0; r < 4; r++) {
    int n = ty + r * 8;
    dst[(size_t)(n0 + n) * K + k0 + tx] = (__bf16)tile[tx][n];
  }
}

__global__ void k_bias_concat(const float* __restrict__ bq, const float* __restrict__ bk,
                              const float* __restrict__ bv, float* __restrict__ out) {
  int i = blockIdx.x * 256 + threadIdx.x;
  if (i >= QKVN) return;
  out[i] = (i < 4096) ? bq[i] : (i < 5120 ? bk[i - 4096] : bv[i - 5120]);
}

// ---------- V transpose: qkv (S x QKVN) v-cols -> vt (NKV x HD x S) ----------
__global__ __launch_bounds__(256) void k_vtrans(const __bf16* __restrict__ qkv,
                                                __bf16* __restrict__ vt) {
  __shared__ __bf16 tile[32][33];
  int tx = threadIdx.x & 31, ty = threadIdx.x >> 5;
  int s0 = blockIdx.x * 32, d0 = blockIdx.y * 32, kv = blockIdx.z;
#pragma unroll
  for (int r = 0; r < 4; r++) {
    int s = ty + r * 8;
    tile[s][tx] = qkv[(size_t)(s0 + s) * QKVN + 5120 + kv * HD + d0 + tx];
  }
  __syncthreads();
#pragma unroll
  for (int r = 0; r < 4; r++) {
    int d = ty + r * 8;
    vt[(size_t)(kv * HD + d0 + d) * S_LEN + s0 + tx] = tile[tx][d];
  }
}

// ---------- GEMM: C (MxN) = (A (MxK) @ BT(NxK)^T + bias) * colscale ----------
template <typename OutT>
__global__ __launch_bounds__(256) void k_gemm_bt(const __bf16* __restrict__ A,
                                                 const __bf16* __restrict__ BT,
                                                 const float* __restrict__ bias,
                                                 OutT* __restrict__ C, int M, int N, int K,
                                                 float oscale, int scale_cols) {
  __shared__ __bf16 Al[128 * 64];
  __shared__ __bf16 Bl[128 * 64];
  const int tid = threadIdx.x;
  const int lane = tid & 63;
  const int w = tid >> 6;
  const int m0 = blockIdx.y * 128;
  const int n0 = blockIdx.x * 128;
  const int wm = (w >> 1) * 64;
  const int wn = (w & 1) * 64;
  const int l15 = lane & 15, lhi = lane >> 4;

  f32x4 acc[4][4];
#pragma unroll
  for (int i = 0; i < 4; i++)
#pragma unroll
    for (int j = 0; j < 4; j++)
#pragma unroll
      for (int e = 0; e < 4; e++) acc[i][j][e] = 0.f;

  for (int kt = 0; kt < K; kt += 64) {
#pragma unroll
    for (int it = 0; it < 4; it++) {
      int idx = it * 256 + tid;
      int row = idx >> 3, slot = idx & 7;
      int scol = ((slot * 16) ^ ((row & 7) << 4)) >> 1;  // element offset in row
      gload_lds16(A + (size_t)(m0 + row) * K + kt + scol, &Al[idx * 8]);
      gload_lds16(BT + (size_t)(n0 + row) * K + kt + scol, &Bl[idx * 8]);
    }
    __syncthreads();
#pragma unroll
    for (int kk = 0; kk < 2; kk++) {
      bf16x8 af[4], bfr[4];
#pragma unroll
      for (int i = 0; i < 4; i++) {
        int ra = wm + i * 16 + l15;
        int ba = (kk * 64 + lhi * 16) ^ ((ra & 7) << 4);
        af[i] = *(const bf16x8*)((const char*)Al + ra * 128 + ba);
        int rb = wn + i * 16 + l15;
        int bb = (kk * 64 + lhi * 16) ^ ((rb & 7) << 4);
        bfr[i] = *(const bf16x8*)((const char*)Bl + rb * 128 + bb);
      }
#pragma unroll
      for (int i = 0; i < 4; i++)
#pragma unroll
        for (int j = 0; j < 4; j++) acc[i][j] = mfma16(af[i], bfr[j], acc[i][j]);
    }
    __syncthreads();
  }
#pragma unroll
  for (int j = 0; j < 4; j++) {
    int col = n0 + wn + j * 16 + l15;
    float bv = bias[col];
    float sc = (col < scale_cols) ? oscale : 1.0f;
#pragma unroll
    for (int i = 0; i < 4; i++) {
      int r0 = m0 + wm + i * 16 + lhi * 4;
#pragma unroll
      for (int rr = 0; rr < 4; rr++) {
        C[(size_t)(r0 + rr) * N + col] = (OutT)((acc[i][j][rr] + bv) * sc);
      }
    }
  }
}

// ---------- causal GQA flash attention, pair-balanced ----------
// grid (16 pairs, 32 heads); block p handles q-tiles p and 31-p (64 rows each).
// Every block does exactly 33 compute-units. K/V double-buffered with counted
// vmcnt so prefetch loads stay in flight across the barrier. Q pre-scaled.
__global__ __launch_bounds__(256) void k_attn(const __bf16* __restrict__ qkv,
                                              const __bf16* __restrict__ vt,
                                              __bf16* __restrict__ o) {
  __shared__ __bf16 Kl[2][64 * 128];
  __shared__ __bf16 Vl[2][128 * 64];
  __shared__ __bf16 Pl[4][32 * 64];
  const int tid = threadIdx.x, lane = tid & 63, w = tid >> 6;
  const int l15 = lane & 15, lhi = lane >> 4;
  const int pair = blockIdx.x, head = blockIdx.y, kvh = head >> 2;
  const int qtA = pair, qtB = 31 - pair;
  const int rowA = qtA * 64 + w * 16;
  const int rowB = qtB * 64 + w * 16;

  // Q fragments (pre-scaled by 1/sqrt(d) in the QKV GEMM epilogue)
  bf16x8 qf[2][4];
#pragma unroll
  for (int qs = 0; qs < 2; qs++) {
    int qr = (qs ? rowB : rowA) + l15;
#pragma unroll
    for (int dk = 0; dk < 4; dk++)
      qf[qs][dk] = *(const bf16x8*)(qkv + (size_t)qr * QKVN + head * HD + dk * 32 + lhi * 8);
  }

  f32x4 acc_o[2][8];
#pragma unroll
  for (int qs = 0; qs < 2; qs++)
#pragma unroll
    for (int ds = 0; ds < 8; ds++)
#pragma unroll
      for (int e = 0; e < 4; e++) acc_o[qs][ds][e] = 0.f;
  float mrow[2][4], lrow[2][4];
#pragma unroll
  for (int qs = 0; qs < 2; qs++)
#pragma unroll
    for (int r = 0; r < 4; r++) { mrow[qs][r] = -INFINITY; lrow[qs][r] = 0.f; }

#define STAGE(buf, ktile)                                                            \
  do {                                                                               \
    const int kk0 = (ktile) * 64;                                                    \
    _Pragma("unroll") for (int it = 0; it < 4; it++) {                               \
      int idx = it * 256 + tid;                                                      \
      int key = idx >> 4, slot = idx & 15;                                           \
      int sb = (slot * 16) ^ ((key & 7) << 4);                                       \
      gload_lds16(qkv + (size_t)(kk0 + key) * QKVN + 4096 + kvh * HD + (sb >> 1),    \
                  &Kl[buf][idx * 8]);                                                \
    }                                                                                \
    _Pragma("unroll") for (int it = 0; it < 4; it++) {                               \
      int idx = it * 256 + tid;                                                      \
      int d = idx >> 3, slot = idx & 7;                                              \
      int sb = (slot * 16) ^ ((d & 7) << 4);                                         \
      gload_lds16(vt + (size_t)(kvh * HD + d) * S_LEN + kk0 + (sb >> 1),             \
                  &Vl[buf][idx * 8]);                                                \
    }                                                                                \
  } while (0)

  const int nkt = qtB + 1;
  STAGE(0, 0);
  for (int kt = 0; kt < nkt; kt++) {
    const int cur = kt & 1;
    if (kt + 1 < nkt) {
      STAGE(cur ^ 1, kt + 1);
      asm volatile("s_waitcnt vmcnt(8)" ::: "memory");  // tile kt landed; kt+1 in flight
    } else {
      asm volatile("s_waitcnt vmcnt(0)" ::: "memory");
    }
    __builtin_amdgcn_s_barrier();
    __builtin_amdgcn_sched_barrier(0);

    const int k0 = kt * 64;
    const bool actA = (kt <= qtA);

    // ---- QK^T ----
    f32x4 sacc[2][4];
#pragma unroll
    for (int ks = 0; ks < 4; ks++)
#pragma unroll
      for (int e = 0; e < 4; e++) { sacc[1][ks][e] = 0.f; sacc[0][ks][e] = 0.f; }
#pragma unroll
    for (int dk = 0; dk < 4; dk++) {
      bf16x8 kf[4];
#pragma unroll
      for (int ks = 0; ks < 4; ks++) {
        int kr = ks * 16 + l15;
        int db = (dk * 64 + lhi * 16) ^ ((kr & 7) << 4);
        kf[ks] = *(const bf16x8*)((const char*)&Kl[cur][0] + kr * 256 + db);
      }
#pragma unroll
      for (int ks = 0; ks < 4; ks++) {
        sacc[1][ks] = mfma16(qf[1][dk], kf[ks], sacc[1][ks]);
        if (actA) sacc[0][ks] = mfma16(qf[0][dk], kf[ks], sacc[0][ks]);
      }
    }

    // ---- online softmax (defer-max, THR=8) ----
#pragma unroll
    for (int qs = 0; qs < 2; qs++) {
      if (qs == 0 && !actA) continue;
      const int qbase = qs ? rowB : rowA;
      const bool diag = (k0 + 63 > qbase);  // only the diagonal tile masks
      float sv[4][4], pm[4];
#pragma unroll
      for (int r = 0; r < 4; r++) {
        int qg = qbase + lhi * 4 + r;
        float mx = -INFINITY;
#pragma unroll
        for (int ks = 0; ks < 4; ks++) {
          int kg = k0 + ks * 16 + l15;
          float s = sacc[qs][ks][r];
          if (diag && kg > qg) s = -INFINITY;
          sv[ks][r] = s;
          mx = fmaxf(mx, s);
        }
        pm[r] = mx;
      }
#pragma unroll
      for (int off = 1; off < 16; off <<= 1)
#pragma unroll
        for (int r = 0; r < 4; r++) pm[r] = fmaxf(pm[r], __shfl_xor(pm[r], off));
      float grow = 0.f;
#pragma unroll
      for (int r = 0; r < 4; r++) grow = fmaxf(grow, pm[r] - mrow[qs][r]);
      if (__any(grow > 8.f)) {
        float corr[4];
#pragma unroll
        for (int r = 0; r < 4; r++) {
          float mn = fmaxf(mrow[qs][r], pm[r]);
          corr[r] = __expf(mrow[qs][r] - mn);
          mrow[qs][r] = mn;
          lrow[qs][r] *= corr[r];
        }
#pragma unroll
        for (int ds = 0; ds < 8; ds++)
#pragma unroll
          for (int r = 0; r < 4; r++) acc_o[qs][ds][r] *= corr[r];
      }
      float ps[4] = {0.f, 0.f, 0.f, 0.f};
#pragma unroll
      for (int ks = 0; ks < 4; ks++) {
        int keyl = ks * 16 + l15;
#pragma unroll
        for (int r = 0; r < 4; r++) {
          int ql = qs * 16 + lhi * 4 + r;
          float p = __expf(sv[ks][r] - mrow[qs][r]);
          ps[r] += p;
          *(__bf16*)((char*)&Pl[w][0] + ql * 128 + ((keyl * 2) ^ ((ql & 7) << 4))) = (__bf16)p;
        }
      }
#pragma unroll
      for (int r = 0; r < 4; r++) lrow[qs][r] += ps[r];
    }

    // ---- PV ----
#pragma unroll
    for (int ks2 = 0; ks2 < 2; ks2++) {
      bf16x8 pf[2];
#pragma unroll
      for (int qs = 0; qs < 2; qs++) {
        if (qs == 0 && !actA) continue;
        int ql = qs * 16 + l15;
        int kb = (ks2 * 64 + lhi * 16) ^ ((ql & 7) << 4);
        pf[qs] = *(const bf16x8*)((const char*)&Pl[w][0] + ql * 128 + kb);
      }
#pragma unroll
      for (int ds = 0; ds < 8; ds++) {
        int dr = ds * 16 + l15;
        int kb = (ks2 * 64 + lhi * 16) ^ ((dr & 7) << 4);
        bf16x8 vf = *(const bf16x8*)((const char*)&Vl[cur][0] + dr * 128 + kb);
        acc_o[1][ds] = mfma16(pf[1], vf, acc_o[1][ds]);
        if (actA) acc_o[0][ds] = mfma16(pf[0], vf, acc_o[0][ds]);
      }
    }
    asm volatile("s_waitcnt lgkmcnt(0)" ::: "memory");
    __builtin_amdgcn_s_barrier();
  }
#undef STAGE

  // ---- finalize ----
#pragma unroll
  for (int qs = 0; qs < 2; qs++) {
#pragma unroll
    for (int off = 1; off < 16; off <<= 1)
#pragma unroll
      for (int r = 0; r < 4; r++) lrow[qs][r] += __shfl_xor(lrow[qs][r], off);
    const int qbase = qs ? rowB : rowA;
#pragma unroll
    for (int r = 0; r < 4; r++) {
      float inv = 1.f / lrow[qs][r];
      int qg = qbase + lhi * 4 + r;
#pragma unroll
      for (int ds = 0; ds < 8; ds++) {
        o[(size_t)qg * OD + head * HD + ds * 16 + l15] = (__bf16)(acc_o[qs][ds][r] * inv);
      }
    }
  }
}

extern "C" void kernel_launch(void* const* d_in, const int* in_sizes, int n_in,
                              void* d_out, int out_size, void* d_ws, size_t ws_size,
                              hipStream_t stream) {
  const float* x  = (const float*)d_in[0];
  // d_in[1] = mask (tril causal; hard-coded in kernel)
  const float* wq = (const float*)d_in[2];
  const float* bq = (const float*)d_in[3];
  const float* wk = (const float*)d_in[4];
  const float* bk = (const float*)d_in[5];
  const float* wv = (const float*)d_in[6];
  const float* bv = (const float*)d_in[7];
  const float* wo = (const float*)d_in[8];
  const float* bo = (const float*)d_in[9];
  float* out = (float*)d_out;

  const size_t MB = 1024 * 1024;
  char* ws = (char*)d_ws;
  __bf16* xb    = (__bf16*)(ws);             //  8 MiB: 2048x2048
  __bf16* wqkvT = (__bf16*)(ws + 8 * MB);    // 24 MiB: 6144x2048 (wq^T|wk^T|wv^T)
  __bf16* woT   = (__bf16*)(ws + 32 * MB);   // 16 MiB: 2048x4096
  __bf16* qkvb  = (__bf16*)(ws + 48 * MB);   // 24 MiB: 2048x6144
  __bf16* vtb   = (__bf16*)(ws + 72 * MB);   //  4 MiB: 8x128x2048
  __bf16* ob    = (__bf16*)(ws + 76 * MB);   // 16 MiB: 2048x4096
  float*  bqkv  = (float*)(ws + 92 * MB);    // 24 KiB

  k_cvt<<<4096, 256, 0, stream>>>(x, xb, HIDDEN * S_LEN);
  k_transpose_cvt<<<dim3(128, 64), 256, 0, stream>>>(wq, wqkvT, HIDDEN, 4096);
  k_transpose_cvt<<<dim3(32, 64), 256, 0, stream>>>(wk, wqkvT + (size_t)4096 * HIDDEN, HIDDEN, 1024);
  k_transpose_cvt<<<dim3(32, 64), 256, 0, stream>>>(wv, wqkvT + (size_t)5120 * HIDDEN, HIDDEN, 1024);
  k_transpose_cvt<<<dim3(64, 128), 256, 0, stream>>>(wo, woT, 4096, HIDDEN);
  k_bias_concat<<<24, 256, 0, stream>>>(bq, bk, bv, bqkv);

  // Q columns pre-scaled by 1/sqrt(HD) in the epilogue
  k_gemm_bt<__bf16><<<dim3(QKVN / 128, S_LEN / 128), 256, 0, stream>>>(
      xb, wqkvT, bqkv, qkvb, S_LEN, QKVN, HIDDEN, 0.08838834764831845f, 4096);
  k_vtrans<<<dim3(S_LEN / 32, HD / 32, NKV), 256, 0, stream>>>(qkvb, vtb);
  k_attn<<<dim3(16, NH), 256, 0, stream>>>(qkvb, vtb, ob);
  k_gemm_bt<float><<<dim3(HIDDEN / 128, S_LEN / 128), 256, 0, stream>>>(
      ob, woT, bo, out, S_LEN, HIDDEN, OD, 1.0f, 0);
}

// Round 4
// 268.401 us; speedup vs baseline: 1.5243x; 1.4086x over previous
//
#include <hip/hip_runtime.h>

#define HIDDEN 2048
#define S_LEN  2048
#define NH     32
#define NKV    8
#define HD     128
#define QKVN   6144   // 4096 q + 1024 k + 1024 v
#define OD     4096   // NH*HD

typedef float  f32x4   __attribute__((ext_vector_type(4)));
typedef float  f32x16  __attribute__((ext_vector_type(16)));
typedef __bf16 bf16x8  __attribute__((ext_vector_type(8)));
typedef __bf16 bf16x4  __attribute__((ext_vector_type(4)));
typedef unsigned int u32;

static __device__ __forceinline__ f32x4 mfma16(bf16x8 a, bf16x8 b, f32x4 c) {
  return __builtin_amdgcn_mfma_f32_16x16x32_bf16(a, b, c, 0, 0, 0);
}
static __device__ __forceinline__ f32x16 mfma32(bf16x8 a, bf16x8 b, f32x16 c) {
  return __builtin_amdgcn_mfma_f32_32x32x16_bf16(a, b, c, 0, 0, 0);
}
static __device__ __forceinline__ void gload_lds16(const void* g, void* l) {
  __builtin_amdgcn_global_load_lds(
      (__attribute__((address_space(1))) void*)(g),
      (__attribute__((address_space(3))) void*)(l), 16, 0, 0);
}
static __device__ __forceinline__ u32 pk_bf16(float lo, float hi) {
  u32 r;
  asm("v_cvt_pk_bf16_f32 %0, %1, %2" : "=v"(r) : "v"(lo), "v"(hi));
  return r;
}

// ---------- fp32 -> bf16 elementwise ----------
__global__ __launch_bounds__(256) void k_cvt(const float* __restrict__ in,
                                             __bf16* __restrict__ out, int n) {
  int i = (blockIdx.x * 256 + threadIdx.x) * 4;
  if (i >= n) return;
  float4 v = *reinterpret_cast<const float4*>(in + i);
  bf16x4 o = {(__bf16)v.x, (__bf16)v.y, (__bf16)v.z, (__bf16)v.w};
  *reinterpret_cast<bf16x4*>(out + i) = o;
}

// ---------- transpose + convert: src (K x N) f32 -> dst (N x K) bf16 ----------
__global__ __launch_bounds__(256) void k_transpose_cvt(const float* __restrict__ src,
                                                       __bf16* __restrict__ dst,
                                                       int K, int N) {
  __shared__ float tile[32][33];
  int tx = threadIdx.x & 31, ty = threadIdx.x >> 5;
  int n0 = blockIdx.x * 32, k0 = blockIdx.y * 32;
#pragma unroll
  for (int r = 0; r < 4; r++) {
    int k = ty + r * 8;
    tile[k][tx] = src[(size_t)(k0 + k) * N + n0 + tx];
  }
  __syncthreads();
#pragma unroll
  for (int r = 0; r < 4; r++) {
    int n = ty + r * 8;
    dst[(size_t)(n0 + n) * K + k0 + tx] = (__bf16)tile[tx][n];
  }
}

__global__ void k_bias_concat(const float* __restrict__ bq, const float* __restrict__ bk,
                              const float* __restrict__ bv, float* __restrict__ out) {
  int i = blockIdx.x * 256 + threadIdx.x;
  if (i >= QKVN) return;
  out[i] = (i < 4096) ? bq[i] : (i < 5120 ? bk[i - 4096] : bv[i - 5120]);
}

// ---------- V transpose: qkv (S x QKVN) v-cols -> vt (NKV x HD x S) ----------
__global__ __launch_bounds__(256) void k_vtrans(const __bf16* __restrict__ qkv,
                                                __bf16* __restrict__ vt) {
  __shared__ __bf16 tile[32][33];
  int tx = threadIdx.x & 31, ty = threadIdx.x >> 5;
  int s0 = blockIdx.x * 32, d0 = blockIdx.y * 32, kv = blockIdx.z;
#pragma unroll
  for (int r = 0; r < 4; r++) {
    int s = ty + r * 8;
    tile[s][tx] = qkv[(size_t)(s0 + s) * QKVN + 5120 + kv * HD + d0 + tx];
  }
  __syncthreads();
#pragma unroll
  for (int r = 0; r < 4; r++) {
    int d = ty + r * 8;
    vt[(size_t)(kv * HD + d0 + d) * S_LEN + s0 + tx] = tile[tx][d];
  }
}

// ---------- GEMM: C (MxN) = (A (MxK) @ BT(NxK)^T + bias) * colscale ----------
template <typename OutT>
__global__ __launch_bounds__(256) void k_gemm_bt(const __bf16* __restrict__ A,
                                                 const __bf16* __restrict__ BT,
                                                 const float* __restrict__ bias,
                                                 OutT* __restrict__ C, int M, int N, int K,
                                                 float oscale, int scale_cols) {
  __shared__ __bf16 Al[128 * 64];
  __shared__ __bf16 Bl[128 * 64];
  const int tid = threadIdx.x;
  const int lane = tid & 63;
  const int w = tid >> 6;
  const int m0 = blockIdx.y * 128;
  const int n0 = blockIdx.x * 128;
  const int wm = (w >> 1) * 64;
  const int wn = (w & 1) * 64;
  const int l15 = lane & 15, lhi = lane >> 4;

  f32x4 acc[4][4];
#pragma unroll
  for (int i = 0; i < 4; i++)
#pragma unroll
    for (int j = 0; j < 4; j++)
#pragma unroll
      for (int e = 0; e < 4; e++) acc[i][j][e] = 0.f;

  for (int kt = 0; kt < K; kt += 64) {
#pragma unroll
    for (int it = 0; it < 4; it++) {
      int idx = it * 256 + tid;
      int row = idx >> 3, slot = idx & 7;
      int scol = ((slot * 16) ^ ((row & 7) << 4)) >> 1;  // element offset in row
      gload_lds16(A + (size_t)(m0 + row) * K + kt + scol, &Al[idx * 8]);
      gload_lds16(BT + (size_t)(n0 + row) * K + kt + scol, &Bl[idx * 8]);
    }
    __syncthreads();
#pragma unroll
    for (int kk = 0; kk < 2; kk++) {
      bf16x8 af[4], bfr[4];
#pragma unroll
      for (int i = 0; i < 4; i++) {
        int ra = wm + i * 16 + l15;
        int ba = (kk * 64 + lhi * 16) ^ ((ra & 7) << 4);
        af[i] = *(const bf16x8*)((const char*)Al + ra * 128 + ba);
        int rb = wn + i * 16 + l15;
        int bb = (kk * 64 + lhi * 16) ^ ((rb & 7) << 4);
        bfr[i] = *(const bf16x8*)((const char*)Bl + rb * 128 + bb);
      }
#pragma unroll
      for (int i = 0; i < 4; i++)
#pragma unroll
        for (int j = 0; j < 4; j++) acc[i][j] = mfma16(af[i], bfr[j], acc[i][j]);
    }
    __syncthreads();
  }
#pragma unroll
  for (int j = 0; j < 4; j++) {
    int col = n0 + wn + j * 16 + l15;
    float bv = bias[col];
    float sc = (col < scale_cols) ? oscale : 1.0f;
#pragma unroll
    for (int i = 0; i < 4; i++) {
      int r0 = m0 + wm + i * 16 + lhi * 4;
#pragma unroll
      for (int rr = 0; rr < 4; rr++) {
        C[(size_t)(r0 + rr) * N + col] = (OutT)((acc[i][j][rr] + bv) * sc);
      }
    }
  }
}

// ---------- causal GQA flash attention: 32x32 MFMA, in-register softmax ----------
// 512 blocks = 16 q-tiles (128 rows) x 32 heads; 4 waves x 32 q-rows each.
// S^T = mfma(K,Q) so q = lane&31 (softmax lane-local); P stays in registers via
// cvt_pk_bf16_f32 + v_permlane32_swap_b32; O^T = mfma(V^T, P) keeps col = q.
// LDS: K/V double-buffered in 8-elem-tiled conflict-free layouts, 64 KiB total.
__global__ __launch_bounds__(256, 2) void k_attn(const __bf16* __restrict__ qkv,
                                                 const __bf16* __restrict__ vt,
                                                 __bf16* __restrict__ o) {
  // Kl[buf][dblk=16][key=64][8 d]; Vl[buf][kblk=8][d=128][8 k]
  __shared__ __bf16 Kl[2][8192];
  __shared__ __bf16 Vl[2][8192];
  const int tid = threadIdx.x, lane = tid & 63, w = tid >> 6;
  const int l31 = lane & 31, h = lane >> 5;

  // block-id pairing: ids i and i+256 get tiles t and 15-t (uniform CU load)
  const int id = blockIdx.x;
  int tile, head;
  if (id < 256) { head = id >> 4; tile = id & 15; }
  else          { head = 16 + ((id - 256) >> 4); tile = 15 - (id & 15); }
  const int kvh = head >> 2;
  const int qbase = tile * 128 + w * 32;
  const int qg = qbase + l31;          // this lane's q row
  const int kdiag = (qbase + 31) >> 6; // last (partial) key tile for this wave
  const int nkt = 2 * tile + 2;

  // Q fragments (pre-scaled by 1/sqrt(d) in QKV GEMM epilogue): B-frag col=q
  bf16x8 qf[8];
  {
    const __bf16* qrow = qkv + (size_t)qg * QKVN + head * HD;
#pragma unroll
    for (int dk = 0; dk < 8; dk++) qf[dk] = *(const bf16x8*)(qrow + dk * 16 + h * 8);
  }

  f32x16 acc[4];  // O^T: col=q=lane&31, row=d (reg-mapped), dt*32 block
#pragma unroll
  for (int dt = 0; dt < 4; dt++)
#pragma unroll
    for (int r = 0; r < 16; r++) acc[dt][r] = 0.f;
  float m = -INFINITY, lsum = 0.f;

#define STAGE(buf, ktile)                                                           \
  do {                                                                              \
    const int kk0 = (ktile) * 64;                                                   \
    _Pragma("unroll") for (int it = 0; it < 4; it++) {                              \
      int c = it * 256 + tid;                                                       \
      int db = c >> 6, key = c & 63;                                                \
      gload_lds16(qkv + (size_t)(kk0 + key) * QKVN + 4096 + kvh * HD + db * 8,      \
                  &Kl[buf][c * 8]);                                                 \
    }                                                                               \
    _Pragma("unroll") for (int it = 0; it < 4; it++) {                              \
      int c = it * 256 + tid;                                                       \
      int kb = c >> 7, d = c & 127;                                                 \
      gload_lds16(vt + (size_t)(kvh * HD + d) * S_LEN + kk0 + kb * 8,               \
                  &Vl[buf][c * 8]);                                                 \
    }                                                                               \
  } while (0)

  STAGE(0, 0);
  __syncthreads();

  for (int kt = 0; kt < nkt; kt++) {
    const int cur = kt & 1;
    if (kt + 1 < nkt) STAGE(cur ^ 1, kt + 1);  // in flight during compute

    if (kt <= kdiag) {
      const char* Kb = (const char*)&Kl[cur][0];
      const char* Vb = (const char*)&Vl[cur][0];
      // ---- QK^T: S^T[key][q], two 32-key blocks ----
      f32x16 sacc[2];
#pragma unroll
      for (int b = 0; b < 2; b++)
#pragma unroll
        for (int r = 0; r < 16; r++) sacc[b][r] = 0.f;
#pragma unroll
      for (int dk = 0; dk < 8; dk++) {
        bf16x8 kf0 = *(const bf16x8*)(Kb + (((dk * 2 + h) * 64) + l31) * 16);
        bf16x8 kf1 = *(const bf16x8*)(Kb + (((dk * 2 + h) * 64) + 32 + l31) * 16);
        sacc[0] = mfma32(kf0, qf[dk], sacc[0]);
        sacc[1] = mfma32(kf1, qf[dk], sacc[1]);
      }
      // ---- softmax (lane-local; q = lane&31) ----
      float p[32];
#pragma unroll
      for (int b = 0; b < 2; b++)
#pragma unroll
        for (int r = 0; r < 16; r++) p[b * 16 + r] = sacc[b][r];
      if (kt == kdiag) {  // mask only on the diagonal tile
        const int k0 = kt * 64;
#pragma unroll
        for (int b = 0; b < 2; b++)
#pragma unroll
          for (int r = 0; r < 16; r++) {
            int keyg = k0 + b * 32 + (r & 3) + 8 * (r >> 2) + 4 * h;
            if (keyg > qg) p[b * 16 + r] = -INFINITY;
          }
      }
      float pm = p[0];
#pragma unroll
      for (int i = 1; i < 32; i++) pm = fmaxf(pm, p[i]);
      pm = fmaxf(pm, __shfl_xor(pm, 32));
      if (__any(pm - m > 8.f)) {  // defer-max (T13)
        float mn = fmaxf(m, pm);
        float corr = __expf(m - mn);
        m = mn;
        lsum *= corr;
#pragma unroll
        for (int dt = 0; dt < 4; dt++)
#pragma unroll
          for (int r = 0; r < 16; r++) acc[dt][r] *= corr;
      }
      float psum = 0.f;
#pragma unroll
      for (int i = 0; i < 32; i++) { p[i] = __expf(p[i] - m); psum += p[i]; }
      lsum += psum;
      // ---- PV: O^T += V^T * P, P-frags built in-register ----
      // B-frag word w needs keys (lane>>5)*8 + {2w,2w+1}. Own regs give
      // W0=(+0,+1) W1=(+2,+3) W2=(+8,+9) W3=(+10,+11) at offset 4h.
      // permlane32_swap(vdst,vsrc): vdst.hi <-> vsrc.lo. swap(W0,W2) makes
      // W0 -> word0 {lo:W0@h0, hi:W2@h0}, W2 -> word2 {lo:W0@h1, hi:W2@h1}.
#pragma unroll
      for (int ks2 = 0; ks2 < 4; ks2++) {
        const int o8 = (ks2 >> 1) * 16 + (ks2 & 1) * 8;
        u32 W0 = pk_bf16(p[o8 + 0], p[o8 + 1]);
        u32 W1 = pk_bf16(p[o8 + 2], p[o8 + 3]);
        u32 W2 = pk_bf16(p[o8 + 4], p[o8 + 5]);
        u32 W3 = pk_bf16(p[o8 + 6], p[o8 + 7]);
        asm("v_permlane32_swap_b32 %0, %1" : "+v"(W0), "+v"(W2));
        asm("v_permlane32_swap_b32 %0, %1" : "+v"(W1), "+v"(W3));
        union { u32 wd[4]; bf16x8 v; } pu;
        pu.wd[0] = W0; pu.wd[1] = W1; pu.wd[2] = W2; pu.wd[3] = W3;
#pragma unroll
        for (int dt = 0; dt < 4; dt++) {
          bf16x8 vf = *(const bf16x8*)(Vb + (((ks2 * 2 + h) * 128) + dt * 32 + l31) * 16);
          acc[dt] = mfma32(vf, pu.v, acc[dt]);
        }
      }
    }
    __syncthreads();  // drains vmcnt: next tile landed; buffers safe to swap
  }
#undef STAGE

  // ---- finalize: combine the two key-halves, normalize, store ----
  lsum += __shfl_xor(lsum, 32);
  const float inv = 1.f / lsum;
  __bf16* orow = o + (size_t)qg * OD + head * HD;
#pragma unroll
  for (int dt = 0; dt < 4; dt++)
#pragma unroll
    for (int rq = 0; rq < 4; rq++) {  // reg quads -> 4 consecutive d
      int d = dt * 32 + 8 * rq + 4 * h;
      bf16x4 ov = {(__bf16)(acc[dt][rq * 4 + 0] * inv), (__bf16)(acc[dt][rq * 4 + 1] * inv),
                   (__bf16)(acc[dt][rq * 4 + 2] * inv), (__bf16)(acc[dt][rq * 4 + 3] * inv)};
      *(bf16x4*)(orow + d) = ov;
    }
}

extern "C" void kernel_launch(void* const* d_in, const int* in_sizes, int n_in,
                              void* d_out, int out_size, void* d_ws, size_t ws_size,
                              hipStream_t stream) {
  const float* x  = (const float*)d_in[0];
  // d_in[1] = mask (tril causal; hard-coded in kernel)
  const float* wq = (const float*)d_in[2];
  const float* bq = (const float*)d_in[3];
  const float* wk = (const float*)d_in[4];
  const float* bk = (const float*)d_in[5];
  const float* wv = (const float*)d_in[6];
  const float* bv = (const float*)d_in[7];
  const float* wo = (const float*)d_in[8];
  const float* bo = (const float*)d_in[9];
  float* out = (float*)d_out;

  const size_t MB = 1024 * 1024;
  char* ws = (char*)d_ws;
  __bf16* xb    = (__bf16*)(ws);             //  8 MiB: 2048x2048
  __bf16* wqkvT = (__bf16*)(ws + 8 * MB);    // 24 MiB: 6144x2048 (wq^T|wk^T|wv^T)
  __bf16* woT   = (__bf16*)(ws + 32 * MB);   // 16 MiB: 2048x4096
  __bf16* qkvb  = (__bf16*)(ws + 48 * MB);   // 24 MiB: 2048x6144
  __bf16* vtb   = (__bf16*)(ws + 72 * MB);   //  4 MiB: 8x128x2048
  __bf16* ob    = (__bf16*)(ws + 76 * MB);   // 16 MiB: 2048x4096
  float*  bqkv  = (float*)(ws + 92 * MB);    // 24 KiB

  k_cvt<<<4096, 256, 0, stream>>>(x, xb, HIDDEN * S_LEN);
  k_transpose_cvt<<<dim3(128, 64), 256, 0, stream>>>(wq, wqkvT, HIDDEN, 4096);
  k_transpose_cvt<<<dim3(32, 64), 256, 0, stream>>>(wk, wqkvT + (size_t)4096 * HIDDEN, HIDDEN, 1024);
  k_transpose_cvt<<<dim3(32, 64), 256, 0, stream>>>(wv, wqkvT + (size_t)5120 * HIDDEN, HIDDEN, 1024);
  k_transpose_cvt<<<dim3(64, 128), 256, 0, stream>>>(wo, woT, 4096, HIDDEN);
  k_bias_concat<<<24, 256, 0, stream>>>(bq, bk, bv, bqkv);

  // Q columns pre-scaled by 1/sqrt(HD) in the epilogue
  k_gemm_bt<__bf16><<<dim3(QKVN / 128, S_LEN / 128), 256, 0, stream>>>(
      xb, wqkvT, bqkv, qkvb, S_LEN, QKVN, HIDDEN, 0.08838834764831845f, 4096);
  k_vtrans<<<dim3(S_LEN / 32, HD / 32, NKV), 256, 0, stream>>>(qkvb, vtb);
  k_attn<<<512, 256, 0, stream>>>(qkvb, vtb, ob);
  k_gemm_bt<float><<<dim3(HIDDEN / 128, S_LEN / 128), 256, 0, stream>>>(
      ob, woT, bo, out, S_LEN, HIDDEN, OD, 1.0f, 0);
}